// Round 17
// baseline (774.714 us; speedup 1.0000x reference)
//
#include <hip/hip_runtime.h>
#include <hip/hip_bf16.h>

#define H 192
#define HH (192*192)
#define NLAYER 13
#define LSTRIDE (2*HH)         // shorts per layer in fragment-ordered weight buffer
#define ASTRIDE 200            // A-tile row stride in shorts (400B, 16B-aligned)

typedef unsigned short u16;
typedef unsigned int u32;

typedef __attribute__((ext_vector_type(8))) short short8;
typedef __attribute__((ext_vector_type(4))) float floatx4;

__device__ __forceinline__ u16 f2bf(float f) {
    u32 u = __float_as_uint(f);
    u32 r = (u + 0x7FFFu + ((u >> 16) & 1u)) >> 16;   // RNE
    return (u16)r;
}
__device__ __forceinline__ float bf2f(u16 h) {
    return __uint_as_float(((u32)h) << 16);
}

// ---------------- CSR construction (scan-free) ----------------

__global__ void hist_kernel(const int* __restrict__ dst, int* __restrict__ counts, int E) {
    int e = blockIdx.x * blockDim.x + threadIdx.x;
    if (e < E) atomicAdd(&counts[dst[e]], 1);
}

__global__ void alloc_kernel(const int* __restrict__ counts, int* __restrict__ rbeg,
                             int* __restrict__ rcnt, int* __restrict__ cursor,
                             int* __restrict__ total, int Nv) {
    int v = blockIdx.x * blockDim.x + threadIdx.x;
    if (v >= Nv) return;
    int c = counts[v];
    int base = atomicAdd(total, c);
    rbeg[v] = base;
    rcnt[v] = c;
    cursor[v] = base;
}

__global__ void scatter_kernel(const int* __restrict__ src, const int* __restrict__ dst,
                               const float* __restrict__ w, int* __restrict__ cursor,
                               int2* __restrict__ ce, int E) {
    int e = blockIdx.x * blockDim.x + threadIdx.x;
    if (e < E) {
        int p = atomicAdd(&cursor[dst[e]], 1);
        int2 pk; pk.x = src[e]; pk.y = __float_as_int(w[e]);
        ce[p] = pk;
    }
}

// ---------------- degree-sorted processing order (counting sort, 64 bins) ----
// Blocks process vertices in degree order so every wave's edge loop runs
// ~mean(cnt) not max(cnt) — removes Poisson-degree imbalance (~1.6x).

__global__ void dhist_kernel(const int* __restrict__ rcnt, int* __restrict__ bins, int Nv) {
    int v = blockIdx.x * blockDim.x + threadIdx.x;
    if (v < Nv) {
        int c = rcnt[v]; if (c > 63) c = 63;
        atomicAdd(&bins[c], 1);
    }
}

__global__ void dscan_kernel(const int* __restrict__ bins, int* __restrict__ binpos) {
    // single block, 64 threads
    __shared__ int s[64];
    int t = threadIdx.x;
    s[t] = bins[t];
    __syncthreads();
    if (t == 0) {
        int run = 0;
        for (int i = 0; i < 64; i++) { int c = s[i]; s[i] = run; run += c; }
    }
    __syncthreads();
    binpos[t] = s[t];
}

__global__ void dplace_kernel(const int* __restrict__ rcnt, int* __restrict__ binpos,
                              int* __restrict__ perm, int Nv) {
    int v = blockIdx.x * blockDim.x + threadIdx.x;
    if (v < Nv) {
        int c = rcnt[v]; if (c > 63) c = 63;
        int p = atomicAdd(&binpos[c], 1);
        perm[p] = v;
    }
}

// ---------------- Weight prep: fragment-ordered ----------------
// Wf[l][group][hl][lane][j], group = ks*12 + nt. lane = quad*16 + col encodes
// B[n=nt*16+col][k=ks*32+quad*8+j]; hi at +0, lo at +512 within the group.

__global__ void wprep_kernel(const float* __restrict__ W, u16* __restrict__ Wf, int total) {
    int idx = blockIdx.x * blockDim.x + threadIdx.x;
    if (idx >= total) return;
    int l = idx / HH;
    int rem = idx - l * HH;
    int k = rem / H;
    int n = rem - k * H;
    float v = W[idx];
    u16 hi = f2bf(v);
    u16 lo = f2bf(v - bf2f(hi));
    int ks = k >> 5, quad = (k >> 3) & 3, j = k & 7;
    int nt = n >> 4, col = n & 15;
    int lane = quad * 16 + col;
    size_t base = (size_t)l * LSTRIDE + (size_t)(ks * 12 + nt) * 1024 + lane * 8 + j;
    Wf[base] = hi;
    Wf[base + 512] = lo;
}

// ---------------- features fp32 -> bf16 ----------------

__global__ void conv_kernel(const float* __restrict__ in, u16* __restrict__ out, int total4) {
    int idx = blockIdx.x * blockDim.x + threadIdx.x;
    if (idx >= total4) return;
    float4 v = ((const float4*)in)[idx];
    ushort4 p;
    p.x = f2bf(v.x); p.y = f2bf(v.y); p.z = f2bf(v.z); p.w = f2bf(v.w);
    ((ushort4*)out)[idx] = p;
}

// ---------------- common fma helper ----------------

__device__ __forceinline__ void fma8(float* acc, uint4 q, float w) {
    u32 u[4] = {q.x, q.y, q.z, q.w};
    #pragma unroll
    for (int i = 0; i < 4; i++) {
        float lo = __uint_as_float(u[i] << 16);
        float hi = __uint_as_float(u[i] & 0xFFFF0000u);
        acc[2*i]     += w * lo;
        acc[2*i + 1] += w * hi;
    }
}

// ---------------- Fused layer: agg = adj @ S ; out = epilogue(agg @ W + b) ---
// RACE RULE: S (gather input) must NEVER alias out_bf/out_f. resid_bf may
// alias S (read-only).
// Block = 384 threads = 16 dst vertices (degree-sorted via perm) x 24 lanes.
// Phase 1: lane owns 8 cols, one uint4/edge, 4-edge unroll -> LDS A-tile.
// Phase 2: 6 waves; wave w does n-tiles {w, w+6}; B-frags direct from
//   fragment-ordered Wf; A via ds_read_b128. Row ids kept in shV[16].
// mode 0: out_bf = bf16(relu(C+b)); mode 1: f=(resid+relu(C+b))*0.5 -> out_bf;
// mode 2: mode 1 + out_f = f (fp32).

__global__ __launch_bounds__(384) void fused_layer(
    const u16* __restrict__ S, const int* __restrict__ rbeg, const int* __restrict__ rcnt,
    const int2* __restrict__ ce, const int* __restrict__ perm,
    const u16* __restrict__ Wf, const float* __restrict__ bias,
    u16* __restrict__ out_bf, float* __restrict__ out_f, const u16* __restrict__ resid_bf,
    int mode, int M)
{
    __shared__ u16 shA[16 * ASTRIDE];    // 6.4 KB A-tile
    __shared__ int shV[16];              // block-local row -> vertex id
    int tid = threadIdx.x;
    int vg = tid / 24;                   // local row 0..15
    int l  = tid - vg * 24;              // lane in vertex, owns cols l*8..l*8+7
    int vi = blockIdx.x * 16 + vg;
    int v = (vi < M) ? perm[vi] : -1;
    if (l == 0) shV[vg] = v;

    float acc1[8] = {};
    if (v >= 0) {
        int beg = rbeg[v], cnt = rcnt[v];
        const int2* cep = ce + beg;
        const u16* Sc = S + l * 8;
        int e = 0;
        for (; e + 3 < cnt; e += 4) {
            int2 p0 = cep[e], p1 = cep[e + 1], p2 = cep[e + 2], p3 = cep[e + 3];
            uint4 q0 = *(const uint4*)(Sc + (size_t)p0.x * H);
            uint4 q1 = *(const uint4*)(Sc + (size_t)p1.x * H);
            uint4 q2 = *(const uint4*)(Sc + (size_t)p2.x * H);
            uint4 q3 = *(const uint4*)(Sc + (size_t)p3.x * H);
            fma8(acc1, q0, __int_as_float(p0.y));
            fma8(acc1, q1, __int_as_float(p1.y));
            fma8(acc1, q2, __int_as_float(p2.y));
            fma8(acc1, q3, __int_as_float(p3.y));
        }
        for (; e < cnt; e++) {
            int2 p0 = cep[e];
            uint4 q0 = *(const uint4*)(Sc + (size_t)p0.x * H);
            fma8(acc1, q0, __int_as_float(p0.y));
        }
    }
    {
        uint4 p;
        p.x = (u32)f2bf(acc1[0]) | ((u32)f2bf(acc1[1]) << 16);
        p.y = (u32)f2bf(acc1[2]) | ((u32)f2bf(acc1[3]) << 16);
        p.z = (u32)f2bf(acc1[4]) | ((u32)f2bf(acc1[5]) << 16);
        p.w = (u32)f2bf(acc1[6]) | ((u32)f2bf(acc1[7]) << 16);
        *(uint4*)&shA[vg * ASTRIDE + l * 8] = p;
    }
    __syncthreads();

    // ---- phase 2: MFMA (6 waves x 2 n-tiles) ----
    int wave = tid >> 6, lane = tid & 63;
    int col = lane & 15, quad = lane >> 4;

    short8 a[6];
    {
        const u16* Ar = &shA[col * ASTRIDE + quad * 8];
        #pragma unroll
        for (int ks = 0; ks < 6; ks++) a[ks] = *(const short8*)(Ar + ks * 32);
    }

    int nt0 = wave, nt1 = wave + 6;
    floatx4 c0 = {0.f, 0.f, 0.f, 0.f}, c1 = {0.f, 0.f, 0.f, 0.f};
    #pragma unroll
    for (int ks = 0; ks < 6; ks++) {
        const u16* g0 = Wf + (size_t)(ks * 12 + nt0) * 1024 + lane * 8;
        const u16* g1 = Wf + (size_t)(ks * 12 + nt1) * 1024 + lane * 8;
        short8 bh0 = *(const short8*)g0;
        short8 bl0 = *(const short8*)(g0 + 512);
        short8 bh1 = *(const short8*)g1;
        short8 bl1 = *(const short8*)(g1 + 512);
        c0 = __builtin_amdgcn_mfma_f32_16x16x32_bf16(a[ks], bh0, c0, 0, 0, 0);
        c0 = __builtin_amdgcn_mfma_f32_16x16x32_bf16(a[ks], bl0, c0, 0, 0, 0);
        c1 = __builtin_amdgcn_mfma_f32_16x16x32_bf16(a[ks], bh1, c1, 0, 0, 0);
        c1 = __builtin_amdgcn_mfma_f32_16x16x32_bf16(a[ks], bl1, c1, 0, 0, 0);
    }

    // ---- epilogue: C layout col=lane&15, local row=quad*4+r -> vertex shV[] --
    #pragma unroll
    for (int half = 0; half < 2; half++) {
        int nt = half ? nt1 : nt0;
        floatx4 cc = half ? c1 : c0;
        int n = nt * 16 + col;
        float b = bias[n];
        #pragma unroll
        for (int r = 0; r < 4; r++) {
            int row = shV[quad * 4 + r];
            if (row >= 0) {
                float z = fmaxf(cc[r] + b, 0.f);
                size_t o = (size_t)row * H + n;
                if (mode >= 1) {
                    float f = (bf2f(resid_bf[o]) + z) * 0.5f;
                    out_bf[o] = f2bf(f);
                    if (mode == 2) out_f[o] = f;
                } else {
                    out_bf[o] = f2bf(z);
                }
            }
        }
    }
}

// ---------------- head gather: sup = adj @ feats_bf (degree-sorted) ----------

__global__ __launch_bounds__(192) void spmm_raw(
    const u16* __restrict__ S, const int* __restrict__ rbeg, const int* __restrict__ rcnt,
    const int2* __restrict__ ce, const int* __restrict__ perm, u16* __restrict__ out, int Nv)
{
    int tid = threadIdx.x;
    int g = tid / 24;
    int l = tid - g * 24;
    int vi = blockIdx.x * 8 + g;
    if (vi >= Nv) return;
    int v = perm[vi];
    int beg = rbeg[v], cnt = rcnt[v];
    const int2* cep = ce + beg;
    const u16* Sc = S + l * 8;
    float acc[8] = {};
    int e = 0;
    for (; e + 3 < cnt; e += 4) {
        int2 p0 = cep[e], p1 = cep[e + 1], p2 = cep[e + 2], p3 = cep[e + 3];
        uint4 q0 = *(const uint4*)(Sc + (size_t)p0.x * H);
        uint4 q1 = *(const uint4*)(Sc + (size_t)p1.x * H);
        uint4 q2 = *(const uint4*)(Sc + (size_t)p2.x * H);
        uint4 q3 = *(const uint4*)(Sc + (size_t)p3.x * H);
        fma8(acc, q0, __int_as_float(p0.y));
        fma8(acc, q1, __int_as_float(p1.y));
        fma8(acc, q2, __int_as_float(p2.y));
        fma8(acc, q3, __int_as_float(p3.y));
    }
    for (; e < cnt; e++) {
        int2 p0 = cep[e];
        uint4 q0 = *(const uint4*)(Sc + (size_t)p0.x * H);
        fma8(acc, q0, __int_as_float(p0.y));
    }
    size_t idx = (size_t)v * H + l * 8;
    ushort4 o0, o1;
    o0.x = f2bf(acc[0]); o0.y = f2bf(acc[1]); o0.z = f2bf(acc[2]); o0.w = f2bf(acc[3]);
    o1.x = f2bf(acc[4]); o1.y = f2bf(acc[5]); o1.z = f2bf(acc[6]); o1.w = f2bf(acc[7]);
    *(ushort4*)&out[idx] = o0;
    *(ushort4*)&out[idx + 4] = o1;
}

// ---------------- Output head: coords = sup @ W_out + b_out ----------------

__global__ void head_kernel(const u16* __restrict__ A, const float* __restrict__ W,
                            const float* __restrict__ b, float* __restrict__ coords, int M) {
    int row = blockIdx.x * blockDim.x + threadIdx.x;
    if (row >= M) return;
    float a0 = b[0], a1 = b[1], a2 = b[2];
    const u16* Ar = A + (size_t)row * H;
    for (int k = 0; k < H; k++) {
        float x = bf2f(Ar[k]);
        a0 += x * W[k * 3 + 0];
        a1 += x * W[k * 3 + 1];
        a2 += x * W[k * 3 + 2];
    }
    coords[row * 3 + 0] = a0;
    coords[row * 3 + 1] = a1;
    coords[row * 3 + 2] = a2;
}

// ---------------- Launch ----------------

extern "C" void kernel_launch(void* const* d_in, const int* in_sizes, int n_in,
                              void* d_out, int out_size, void* d_ws, size_t ws_size,
                              hipStream_t stream) {
    const float* features = (const float*)d_in[0];
    const int*   edge_src = (const int*)d_in[1];
    const int*   edge_dst = (const int*)d_in[2];
    const float* edge_w   = (const float*)d_in[3];
    const float* Ws       = (const float*)d_in[4];
    const float* bs       = (const float*)d_in[5];
    const float* W_out    = (const float*)d_in[6];
    const float* b_out    = (const float*)d_in[7];

    const int N = in_sizes[0] / H;
    const int E = in_sizes[1];

    float* coords = (float*)d_out;
    float* feats  = coords + (size_t)N * 3;   // fp32 final feats (written at gc13 only)

    char* wptr = (char*)d_ws;
    u16* fbf  = (u16*)wptr;   wptr += (size_t)N * H * sizeof(u16);  // bf16 features
    u16* xb   = (u16*)wptr;   wptr += (size_t)N * H * sizeof(u16);  // x buffer
    u16* fA   = (u16*)wptr;   wptr += (size_t)N * H * sizeof(u16);  // feats ping
    u16* fB   = (u16*)wptr;   wptr += (size_t)N * H * sizeof(u16);  // feats pong
    u16* sup  = (u16*)wptr;   wptr += (size_t)N * H * sizeof(u16);  // head agg
    u16* Wf   = (u16*)wptr;   wptr += (size_t)NLAYER * LSTRIDE * sizeof(u16);
    int* counts = (int*)wptr; wptr += (size_t)N * sizeof(int);
    int* total  = (int*)wptr; wptr += 4;
    int* bins   = (int*)wptr; wptr += 64 * sizeof(int);
    int* binpos = (int*)wptr; wptr += 64 * sizeof(int);
    int* rbeg   = (int*)wptr; wptr += (size_t)N * sizeof(int);
    int* rcnt   = (int*)wptr; wptr += (size_t)N * sizeof(int);
    int* cursor = (int*)wptr; wptr += (size_t)N * sizeof(int);
    int* perm   = (int*)wptr; wptr += (size_t)N * sizeof(int);
    int2* ce    = (int2*)wptr; wptr += (size_t)E * sizeof(int2);

    // --- build CSR (dst-indexed, scan-free) + degree-sorted order ---
    hipMemsetAsync(counts, 0, ((size_t)N + 1 + 64) * sizeof(int), stream);  // counts+total+bins
    hist_kernel<<<(E + 255) / 256, 256, 0, stream>>>(edge_dst, counts, E);
    alloc_kernel<<<(N + 255) / 256, 256, 0, stream>>>(counts, rbeg, rcnt, cursor, total, N);
    scatter_kernel<<<(E + 255) / 256, 256, 0, stream>>>(edge_src, edge_dst, edge_w,
                                                        cursor, ce, E);
    dhist_kernel<<<(N + 255) / 256, 256, 0, stream>>>(rcnt, bins, N);
    dscan_kernel<<<1, 64, 0, stream>>>(bins, binpos);
    dplace_kernel<<<(N + 255) / 256, 256, 0, stream>>>(rcnt, binpos, perm, N);

    // --- weight split + fragment reorder + feature conversion ---
    int wtotal = NLAYER * HH;
    wprep_kernel<<<(wtotal + 255) / 256, 256, 0, stream>>>(Ws, Wf, wtotal);
    int c4 = N * H / 4;
    conv_kernel<<<(c4 + 255) / 256, 256, 0, stream>>>(features, fbf, c4);

    int lb = (N + 15) / 16;              // fused-layer blocks
    int VC = (N + 7) / 8;

    // L0: x0 = relu((adj@fbf) W0 + b0)            [gather fbf -> write xb]
    fused_layer<<<lb, 384, 0, stream>>>(fbf, rbeg, rcnt, ce, perm, Wf + 0 * (size_t)LSTRIDE,
                                        bs + 0 * H, xb, nullptr, nullptr, 0, N);
    // L1: fA = (fbf + relu((adj@xb) W1 + b1))/2   [gather xb -> write fA, resid fbf RO]
    fused_layer<<<lb, 384, 0, stream>>>(xb, rbeg, rcnt, ce, perm, Wf + 1 * (size_t)LSTRIDE,
                                        bs + 1 * H, fA, nullptr, fbf, 1, N);

    // blocks 2-6: ping-pong cur/nxt so gather input never aliases output
    u16* cur = fA;
    u16* nxt = fB;
    for (int i = 2; i < 12; i += 2) {
        fused_layer<<<lb, 384, 0, stream>>>(cur, rbeg, rcnt, ce, perm, Wf + (size_t)i * LSTRIDE,
                                            bs + (size_t)i * H, xb, nullptr, nullptr, 0, N);
        fused_layer<<<lb, 384, 0, stream>>>(xb, rbeg, rcnt, ce, perm, Wf + (size_t)(i+1) * LSTRIDE,
                                            bs + (size_t)(i+1) * H, nxt, nullptr, cur, 1, N);
        u16* t = cur; cur = nxt; nxt = t;
    }

    // gc13: gather cur -> write nxt (+ fp32 feats to d_out); resid cur RO
    fused_layer<<<lb, 384, 0, stream>>>(cur, rbeg, rcnt, ce, perm, Wf + 12 * (size_t)LSTRIDE,
                                        bs + 12 * H, nxt, feats, cur, 2, N);

    // head: coords = (adj@nxt) W_out + b_out
    spmm_raw<<<VC, 192, 0, stream>>>(nxt, rbeg, rcnt, ce, perm, sup, N);
    head_kernel<<<(N + 255) / 256, 256, 0, stream>>>(sup, W_out, b_out, coords, N);
}

// Round 18
// 604.143 us; speedup vs baseline: 1.2823x; 1.2823x over previous
//
#include <hip/hip_runtime.h>
#include <hip/hip_bf16.h>

#define H 192
#define HH (192*192)
#define NLAYER 13
#define LSTRIDE (2*HH)         // shorts per layer in fragment-ordered weight buffer
#define ASTRIDE 200            // A-tile row stride in shorts (400B, 16B-aligned)

typedef unsigned short u16;
typedef unsigned int u32;

typedef __attribute__((ext_vector_type(8))) short short8;
typedef __attribute__((ext_vector_type(4))) float floatx4;

__device__ __forceinline__ u16 f2bf(float f) {
    u32 u = __float_as_uint(f);
    u32 r = (u + 0x7FFFu + ((u >> 16) & 1u)) >> 16;   // RNE
    return (u16)r;
}
__device__ __forceinline__ float bf2f(u16 h) {
    return __uint_as_float(((u32)h) << 16);
}

// ---------------- CSR construction (scan-free), src-range-sorted rows --------
// Edges within each dst row are bucketed by src range (3 ranges of ~N/3).
// All gather blocks then sweep range 0 -> 1 -> 2 in lockstep-ish order, so the
// co-resident working set at any time is ~3.2MB of S rows (fits 4MB XCD L2).

__global__ void hist2_kernel(const int* __restrict__ src, const int* __restrict__ dst,
                             int* __restrict__ counts2, int E, int t1, int t2) {
    int e = blockIdx.x * blockDim.x + threadIdx.x;
    if (e < E) {
        int s = src[e];
        int r = (s >= t2) ? 2 : ((s >= t1) ? 1 : 0);
        atomicAdd(&counts2[dst[e] * 4 + r], 1);
    }
}

__global__ void alloc2_kernel(const int* __restrict__ counts2, int* __restrict__ rbeg,
                              int* __restrict__ rcnt, int* __restrict__ cursor,
                              int* __restrict__ total, int Nv) {
    int v = blockIdx.x * blockDim.x + threadIdx.x;
    if (v >= Nv) return;
    int c0 = counts2[v * 4 + 0];
    int c1 = counts2[v * 4 + 1];
    int c2 = counts2[v * 4 + 2];
    int tot = c0 + c1 + c2;
    int base = atomicAdd(total, tot);    // uniform-address: wave-coalesced by compiler
    rbeg[v] = base;
    rcnt[v] = tot;
    cursor[v * 4 + 0] = base;
    cursor[v * 4 + 1] = base + c0;
    cursor[v * 4 + 2] = base + c0 + c1;
}

__global__ void scatter2_kernel(const int* __restrict__ src, const int* __restrict__ dst,
                                const float* __restrict__ w, int* __restrict__ cursor,
                                int2* __restrict__ ce, int E, int t1, int t2) {
    int e = blockIdx.x * blockDim.x + threadIdx.x;
    if (e < E) {
        int s = src[e];
        int r = (s >= t2) ? 2 : ((s >= t1) ? 1 : 0);
        int p = atomicAdd(&cursor[dst[e] * 4 + r], 1);
        int2 pk; pk.x = s; pk.y = __float_as_int(w[e]);
        ce[p] = pk;
    }
}

// ---------------- Weight prep: fragment-ordered ----------------
// Wf[l][group][hl][lane][j], group = ks*12 + nt. lane = quad*16 + col encodes
// B[n=nt*16+col][k=ks*32+quad*8+j]; hi at +0, lo at +512 within the group.

__global__ void wprep_kernel(const float* __restrict__ W, u16* __restrict__ Wf, int total) {
    int idx = blockIdx.x * blockDim.x + threadIdx.x;
    if (idx >= total) return;
    int l = idx / HH;
    int rem = idx - l * HH;
    int k = rem / H;
    int n = rem - k * H;
    float v = W[idx];
    u16 hi = f2bf(v);
    u16 lo = f2bf(v - bf2f(hi));
    int ks = k >> 5, quad = (k >> 3) & 3, j = k & 7;
    int nt = n >> 4, col = n & 15;
    int lane = quad * 16 + col;
    size_t base = (size_t)l * LSTRIDE + (size_t)(ks * 12 + nt) * 1024 + lane * 8 + j;
    Wf[base] = hi;
    Wf[base + 512] = lo;
}

// ---------------- features fp32 -> bf16 ----------------

__global__ void conv_kernel(const float* __restrict__ in, u16* __restrict__ out, int total4) {
    int idx = blockIdx.x * blockDim.x + threadIdx.x;
    if (idx >= total4) return;
    float4 v = ((const float4*)in)[idx];
    ushort4 p;
    p.x = f2bf(v.x); p.y = f2bf(v.y); p.z = f2bf(v.z); p.w = f2bf(v.w);
    ((ushort4*)out)[idx] = p;
}

// ---------------- common fma helper ----------------

__device__ __forceinline__ void fma8(float* acc, uint4 q, float w) {
    u32 u[4] = {q.x, q.y, q.z, q.w};
    #pragma unroll
    for (int i = 0; i < 4; i++) {
        float lo = __uint_as_float(u[i] << 16);
        float hi = __uint_as_float(u[i] & 0xFFFF0000u);
        acc[2*i]     += w * lo;
        acc[2*i + 1] += w * hi;
    }
}

// ---------------- Fused layer: agg = adj @ S ; out = epilogue(agg @ W + b) ---
// RACE RULE: S (gather input) must NEVER alias out_bf/out_f. resid_bf may
// alias S (read-only).
// Block = 384 threads = 16 dst vertices x 24 lanes.
// Phase 1: lane owns 8 cols, one uint4/edge, 4-edge unroll -> LDS A-tile.
//   (edges are src-range-sorted: temporal L2 locality across all blocks)
// Phase 2: 6 waves; wave w does n-tiles {w, w+6}; B-frags direct from
//   fragment-ordered Wf (lane-contiguous 16B, L2-hot); A via ds_read_b128.
// mode 0: out_bf = bf16(relu(C+b)); mode 1: f=(resid+relu(C+b))*0.5 -> out_bf;
// mode 2: mode 1 + out_f = f (fp32).

__global__ __launch_bounds__(384) void fused_layer(
    const u16* __restrict__ S, const int* __restrict__ rbeg, const int* __restrict__ rcnt,
    const int2* __restrict__ ce, const u16* __restrict__ Wf, const float* __restrict__ bias,
    u16* __restrict__ out_bf, float* __restrict__ out_f, const u16* __restrict__ resid_bf,
    int mode, int M)
{
    __shared__ u16 shA[16 * ASTRIDE];    // 6.4 KB A-tile
    int tid = threadIdx.x;
    int vg = tid / 24;                   // vertex 0..15
    int l  = tid - vg * 24;              // lane in vertex, owns cols l*8..l*8+7
    int v = blockIdx.x * 16 + vg;

    float acc1[8] = {};
    if (v < M) {
        int beg = rbeg[v], cnt = rcnt[v];
        const int2* cep = ce + beg;
        const u16* Sc = S + l * 8;
        int e = 0;
        for (; e + 3 < cnt; e += 4) {
            int2 p0 = cep[e], p1 = cep[e + 1], p2 = cep[e + 2], p3 = cep[e + 3];
            uint4 q0 = *(const uint4*)(Sc + (size_t)p0.x * H);
            uint4 q1 = *(const uint4*)(Sc + (size_t)p1.x * H);
            uint4 q2 = *(const uint4*)(Sc + (size_t)p2.x * H);
            uint4 q3 = *(const uint4*)(Sc + (size_t)p3.x * H);
            fma8(acc1, q0, __int_as_float(p0.y));
            fma8(acc1, q1, __int_as_float(p1.y));
            fma8(acc1, q2, __int_as_float(p2.y));
            fma8(acc1, q3, __int_as_float(p3.y));
        }
        for (; e < cnt; e++) {
            int2 p0 = cep[e];
            uint4 q0 = *(const uint4*)(Sc + (size_t)p0.x * H);
            fma8(acc1, q0, __int_as_float(p0.y));
        }
    }
    {
        uint4 p;
        p.x = (u32)f2bf(acc1[0]) | ((u32)f2bf(acc1[1]) << 16);
        p.y = (u32)f2bf(acc1[2]) | ((u32)f2bf(acc1[3]) << 16);
        p.z = (u32)f2bf(acc1[4]) | ((u32)f2bf(acc1[5]) << 16);
        p.w = (u32)f2bf(acc1[6]) | ((u32)f2bf(acc1[7]) << 16);
        *(uint4*)&shA[vg * ASTRIDE + l * 8] = p;
    }
    __syncthreads();

    // ---- phase 2: MFMA (6 waves x 2 n-tiles) ----
    int wave = tid >> 6, lane = tid & 63;
    int col = lane & 15, quad = lane >> 4;

    short8 a[6];
    {
        const u16* Ar = &shA[col * ASTRIDE + quad * 8];
        #pragma unroll
        for (int ks = 0; ks < 6; ks++) a[ks] = *(const short8*)(Ar + ks * 32);
    }

    int nt0 = wave, nt1 = wave + 6;
    floatx4 c0 = {0.f, 0.f, 0.f, 0.f}, c1 = {0.f, 0.f, 0.f, 0.f};
    #pragma unroll
    for (int ks = 0; ks < 6; ks++) {
        const u16* g0 = Wf + (size_t)(ks * 12 + nt0) * 1024 + lane * 8;
        const u16* g1 = Wf + (size_t)(ks * 12 + nt1) * 1024 + lane * 8;
        short8 bh0 = *(const short8*)g0;
        short8 bl0 = *(const short8*)(g0 + 512);
        short8 bh1 = *(const short8*)g1;
        short8 bl1 = *(const short8*)(g1 + 512);
        c0 = __builtin_amdgcn_mfma_f32_16x16x32_bf16(a[ks], bh0, c0, 0, 0, 0);
        c0 = __builtin_amdgcn_mfma_f32_16x16x32_bf16(a[ks], bl0, c0, 0, 0, 0);
        c1 = __builtin_amdgcn_mfma_f32_16x16x32_bf16(a[ks], bh1, c1, 0, 0, 0);
        c1 = __builtin_amdgcn_mfma_f32_16x16x32_bf16(a[ks], bl1, c1, 0, 0, 0);
    }

    // ---- epilogue: C layout col=lane&15, row=quad*4+r ----
    int rm = blockIdx.x * 16;
    #pragma unroll
    for (int half = 0; half < 2; half++) {
        int nt = half ? nt1 : nt0;
        floatx4 cc = half ? c1 : c0;
        int n = nt * 16 + col;
        float b = bias[n];
        #pragma unroll
        for (int r = 0; r < 4; r++) {
            int row = rm + quad * 4 + r;
            if (row < M) {
                float z = fmaxf(cc[r] + b, 0.f);
                size_t o = (size_t)row * H + n;
                if (mode >= 1) {
                    float f = (bf2f(resid_bf[o]) + z) * 0.5f;
                    out_bf[o] = f2bf(f);
                    if (mode == 2) out_f[o] = f;
                } else {
                    out_bf[o] = f2bf(z);
                }
            }
        }
    }
}

// ---------------- head gather: sup = adj @ feats_bf ----------------

__global__ __launch_bounds__(192) void spmm_raw(
    const u16* __restrict__ S, const int* __restrict__ rbeg, const int* __restrict__ rcnt,
    const int2* __restrict__ ce, u16* __restrict__ out, int Nv)
{
    int tid = threadIdx.x;
    int g = tid / 24;
    int l = tid - g * 24;
    int v = blockIdx.x * 8 + g;
    if (v >= Nv) return;
    int beg = rbeg[v], cnt = rcnt[v];
    const int2* cep = ce + beg;
    const u16* Sc = S + l * 8;
    float acc[8] = {};
    int e = 0;
    for (; e + 3 < cnt; e += 4) {
        int2 p0 = cep[e], p1 = cep[e + 1], p2 = cep[e + 2], p3 = cep[e + 3];
        uint4 q0 = *(const uint4*)(Sc + (size_t)p0.x * H);
        uint4 q1 = *(const uint4*)(Sc + (size_t)p1.x * H);
        uint4 q2 = *(const uint4*)(Sc + (size_t)p2.x * H);
        uint4 q3 = *(const uint4*)(Sc + (size_t)p3.x * H);
        fma8(acc, q0, __int_as_float(p0.y));
        fma8(acc, q1, __int_as_float(p1.y));
        fma8(acc, q2, __int_as_float(p2.y));
        fma8(acc, q3, __int_as_float(p3.y));
    }
    for (; e < cnt; e++) {
        int2 p0 = cep[e];
        uint4 q0 = *(const uint4*)(Sc + (size_t)p0.x * H);
        fma8(acc, q0, __int_as_float(p0.y));
    }
    size_t idx = (size_t)v * H + l * 8;
    ushort4 o0, o1;
    o0.x = f2bf(acc[0]); o0.y = f2bf(acc[1]); o0.z = f2bf(acc[2]); o0.w = f2bf(acc[3]);
    o1.x = f2bf(acc[4]); o1.y = f2bf(acc[5]); o1.z = f2bf(acc[6]); o1.w = f2bf(acc[7]);
    *(ushort4*)&out[idx] = o0;
    *(ushort4*)&out[idx + 4] = o1;
}

// ---------------- Output head: coords = sup @ W_out + b_out ----------------

__global__ void head_kernel(const u16* __restrict__ A, const float* __restrict__ W,
                            const float* __restrict__ b, float* __restrict__ coords, int M) {
    int row = blockIdx.x * blockDim.x + threadIdx.x;
    if (row >= M) return;
    float a0 = b[0], a1 = b[1], a2 = b[2];
    const u16* Ar = A + (size_t)row * H;
    for (int k = 0; k < H; k++) {
        float x = bf2f(Ar[k]);
        a0 += x * W[k * 3 + 0];
        a1 += x * W[k * 3 + 1];
        a2 += x * W[k * 3 + 2];
    }
    coords[row * 3 + 0] = a0;
    coords[row * 3 + 1] = a1;
    coords[row * 3 + 2] = a2;
}

// ---------------- Launch ----------------

extern "C" void kernel_launch(void* const* d_in, const int* in_sizes, int n_in,
                              void* d_out, int out_size, void* d_ws, size_t ws_size,
                              hipStream_t stream) {
    const float* features = (const float*)d_in[0];
    const int*   edge_src = (const int*)d_in[1];
    const int*   edge_dst = (const int*)d_in[2];
    const float* edge_w   = (const float*)d_in[3];
    const float* Ws       = (const float*)d_in[4];
    const float* bs       = (const float*)d_in[5];
    const float* W_out    = (const float*)d_in[6];
    const float* b_out    = (const float*)d_in[7];

    const int N = in_sizes[0] / H;
    const int E = in_sizes[1];
    const int t1 = N / 3, t2 = 2 * N / 3;

    float* coords = (float*)d_out;
    float* feats  = coords + (size_t)N * 3;   // fp32 final feats (written at gc13 only)

    char* wptr = (char*)d_ws;
    u16* fbf  = (u16*)wptr;   wptr += (size_t)N * H * sizeof(u16);  // bf16 features
    u16* xb   = (u16*)wptr;   wptr += (size_t)N * H * sizeof(u16);  // x buffer
    u16* fA   = (u16*)wptr;   wptr += (size_t)N * H * sizeof(u16);  // feats ping
    u16* fB   = (u16*)wptr;   wptr += (size_t)N * H * sizeof(u16);  // feats pong
    u16* sup  = (u16*)wptr;   wptr += (size_t)N * H * sizeof(u16);  // head agg
    u16* Wf   = (u16*)wptr;   wptr += (size_t)NLAYER * LSTRIDE * sizeof(u16);
    int* counts2 = (int*)wptr; wptr += (size_t)N * 4 * sizeof(int);
    int* total   = (int*)wptr; wptr += 4;
    int* rbeg    = (int*)wptr; wptr += (size_t)N * sizeof(int);
    int* rcnt    = (int*)wptr; wptr += (size_t)N * sizeof(int);
    int* cursor  = (int*)wptr; wptr += (size_t)N * 4 * sizeof(int);
    int2* ce     = (int2*)wptr; wptr += (size_t)E * sizeof(int2);

    // --- build CSR (dst-indexed, scan-free, src-range-sorted rows) ---
    hipMemsetAsync(counts2, 0, ((size_t)N * 4 + 1) * sizeof(int), stream);  // counts2 + total
    hist2_kernel<<<(E + 255) / 256, 256, 0, stream>>>(edge_src, edge_dst, counts2, E, t1, t2);
    alloc2_kernel<<<(N + 255) / 256, 256, 0, stream>>>(counts2, rbeg, rcnt, cursor, total, N);
    scatter2_kernel<<<(E + 255) / 256, 256, 0, stream>>>(edge_src, edge_dst, edge_w,
                                                         cursor, ce, E, t1, t2);

    // --- weight split + fragment reorder + feature conversion ---
    int wtotal = NLAYER * HH;
    wprep_kernel<<<(wtotal + 255) / 256, 256, 0, stream>>>(Ws, Wf, wtotal);
    int c4 = N * H / 4;
    conv_kernel<<<(c4 + 255) / 256, 256, 0, stream>>>(features, fbf, c4);

    int lb = (N + 15) / 16;              // fused-layer blocks
    int VC = (N + 7) / 8;

    // L0: x0 = relu((adj@fbf) W0 + b0)            [gather fbf -> write xb]
    fused_layer<<<lb, 384, 0, stream>>>(fbf, rbeg, rcnt, ce, Wf + 0 * (size_t)LSTRIDE,
                                        bs + 0 * H, xb, nullptr, nullptr, 0, N);
    // L1: fA = (fbf + relu((adj@xb) W1 + b1))/2   [gather xb -> write fA, resid fbf RO]
    fused_layer<<<lb, 384, 0, stream>>>(xb, rbeg, rcnt, ce, Wf + 1 * (size_t)LSTRIDE,
                                        bs + 1 * H, fA, nullptr, fbf, 1, N);

    // blocks 2-6: ping-pong cur/nxt so gather input never aliases output
    u16* cur = fA;
    u16* nxt = fB;
    for (int i = 2; i < 12; i += 2) {
        fused_layer<<<lb, 384, 0, stream>>>(cur, rbeg, rcnt, ce, Wf + (size_t)i * LSTRIDE,
                                            bs + (size_t)i * H, xb, nullptr, nullptr, 0, N);
        fused_layer<<<lb, 384, 0, stream>>>(xb, rbeg, rcnt, ce, Wf + (size_t)(i+1) * LSTRIDE,
                                            bs + (size_t)(i+1) * H, nxt, nullptr, cur, 1, N);
        u16* t = cur; cur = nxt; nxt = t;
    }

    // gc13: gather cur -> write nxt (+ fp32 feats to d_out); resid cur RO
    fused_layer<<<lb, 384, 0, stream>>>(cur, rbeg, rcnt, ce, Wf + 12 * (size_t)LSTRIDE,
                                        bs + 12 * H, nxt, feats, cur, 2, N);

    // head: coords = (adj@nxt) W_out + b_out
    spmm_raw<<<VC, 192, 0, stream>>>(nxt, rbeg, rcnt, ce, sup, N);
    head_kernel<<<(N + 255) / 256, 256, 0, stream>>>(sup, W_out, b_out, coords, N);
}